// Round 2
// baseline (325.199 us; speedup 1.0000x reference)
//
#include <hip/hip_runtime.h>

#define N_TOT 400000
#define NBLK  6250          // N_TOT / 64 voxels per block
#define NWAVE (NBLK * 4)
#define NELEM (N_TOT * 16)

typedef __attribute__((ext_vector_type(8))) short short8;
typedef __attribute__((ext_vector_type(4))) float f32x4;
typedef __attribute__((ext_vector_type(4))) unsigned short us4;
typedef __attribute__((ext_vector_type(4))) int i32x4;

__device__ __forceinline__ unsigned short f2bf(float x) {
    unsigned int u = __float_as_uint(x);
    u += 0x7FFFu + ((u >> 16) & 1u);       // round-to-nearest-even
    return (unsigned short)(u >> 16);
}

// Build bf16 B-fragments for all 5 layers x 14 k-pairs.
// mfma_f32_16x16x32_bf16 B layout: lane l holds B[k=8*(l>>4)+j][col=l&15].
// k-pair p covers offsets 2p (klocal 0..15) and 2p+1 (klocal 16..31); offset 27 = zero pad.
__global__ __launch_bounds__(64) void wfrag_k(const float* __restrict__ w_in,
                                              const float* __restrict__ wbs,
                                              unsigned short* __restrict__ wfrag) {
    int b = blockIdx.x;            // L*14 + p
    int L = b / 14, p = b % 14;
    int l = threadIdx.x;
    int g = l >> 4, col = l & 15;
    int k = 2 * p + (g >> 1);
    int cib = (g & 1) * 8;
    unsigned short v[8];
#pragma unroll
    for (int j = 0; j < 8; ++j) {
        float w = 0.f;
        if (k < 27) {
            int ci = cib + j;
            w = (L == 0) ? w_in[(k * 16 + ci) * 16 + col]
                         : wbs[(((L - 1) * 27 + k) * 16 + ci) * 16 + col];
        }
        v[j] = f2bf(w);
    }
    unsigned short* dst = wfrag + (size_t)(b * 64 + l) * 8;
#pragma unroll
    for (int j = 0; j < 8; ++j) dst[j] = v[j];
}

__global__ __launch_bounds__(256) void cvt_k(const float* __restrict__ in,
                                             unsigned short* __restrict__ out) {
    int i = (blockIdx.x * 256 + threadIdx.x) * 4;
    f32x4 v = *reinterpret_cast<const f32x4*>(in + i);
    us4 o = { f2bf(v[0]), f2bf(v[1]), f2bf(v[2]), f2bf(v[3]) };
    *reinterpret_cast<us4*>(out + i) = o;
}

// Pack per-lane neighbor indices: idxpk[w][j][p] = nbr[2p + (j>>4)][w*16 + (j&15)]
// (j in [0,32): ksel*16 + rc; p in [0,16), entries p>=14 or k>=27 = -1).
// Conv wave w lane l reads row j = (l>>5)*16 + (l&15) with 4 dwordx4 loads.
__global__ __launch_bounds__(256) void prep_k(const int* __restrict__ nbr,
                                              int* __restrict__ idxpk) {
    int t = blockIdx.x * 256 + threadIdx.x;          // one entry per thread
    int p = t & 15;
    int j = (t >> 4) & 31;
    int w = t >> 9;
    int k = 2 * p + (j >> 4);
    int v = w * 16 + (j & 15);
    int val = -1;
    if (p < 14 && k < 27) val = nbr[(size_t)k * N_TOT + v];
    idxpk[t] = val;
}

// Gather-MFMA submanifold conv: 1 wave = 16 voxels, 4 waves/block.
// Weights for all 27 offsets staged in LDS once per block; per-pair wave-uniform
// skip when no lane has a valid neighbor (~32% of pairs at 3.5% density).
__global__ __launch_bounds__(256) void conv_k(const unsigned short* __restrict__ feats,
                                              const int* __restrict__ nbr,
                                              const int* __restrict__ idxpk,
                                              const unsigned short* __restrict__ wfrag,
                                              float* __restrict__ out,
                                              float* __restrict__ partials) {
    __shared__ unsigned short wlds[14 * 64 * 8];   // 14336 B
    __shared__ float red[128];

    // cooperative wfrag stage: 14336 B = 896 x 16 B
    {
        const f32x4* src = reinterpret_cast<const f32x4*>(wfrag);
        f32x4* dst = reinterpret_cast<f32x4*>(wlds);
        for (int j = threadIdx.x; j < 896; j += 256) dst[j] = src[j];
    }
    __syncthreads();

    const int lane = threadIdx.x & 63;
    const int wv   = threadIdx.x >> 6;
    const int w    = blockIdx.x * 4 + wv;
    const int v0   = w * 16;
    const int g    = lane >> 4;
    const int rc   = lane & 15;        // A-row / B-col
    const int half = (g & 1) * 8;      // which 8 input channels this lane loads
    const int ksel = g >> 1;           // which offset of the pair

    int idxs[16];
    if (idxpk) {
        const int* base = idxpk + ((size_t)w * 32 + (ksel * 16 + rc)) * 16;
#pragma unroll
        for (int q = 0; q < 4; ++q)
            *reinterpret_cast<i32x4*>(&idxs[q * 4]) =
                *reinterpret_cast<const i32x4*>(base + q * 4);
    } else {
#pragma unroll
        for (int p = 0; p < 14; ++p) {
            int k = 2 * p + ksel;
            idxs[p] = (k < 27) ? nbr[(size_t)k * N_TOT + v0 + rc] : -1;
        }
    }

    unsigned anym = 0;
#pragma unroll
    for (int p = 0; p < 14; ++p)
        if (__any(idxs[p] >= 0)) anym |= (1u << p);

    short8 a[14];
#pragma unroll
    for (int p = 0; p < 14; ++p) {
        if (anym & (1u << p)) {
            int idx = idxs[p];
            bool valid = idx >= 0;
            int ci = valid ? idx : 0;
            short8 t = *reinterpret_cast<const short8*>(feats + (size_t)ci * 16 + half);
            if (!valid) { short8 z = {0, 0, 0, 0, 0, 0, 0, 0}; t = z; }
            a[p] = t;
        }
    }

    f32x4 acc = {0.f, 0.f, 0.f, 0.f};
#pragma unroll
    for (int p = 0; p < 14; ++p) {
        if (anym & (1u << p)) {
            short8 b = *reinterpret_cast<const short8*>(&wlds[(p * 64 + lane) * 8]);
            acc = __builtin_amdgcn_mfma_f32_16x16x32_bf16(a[p], b, acc, 0, 0, 0);
        }
    }

    // C/D layout: col = lane&15, row = (lane>>4)*4 + reg  [m89/m91 verified]
#pragma unroll
    for (int i = 0; i < 4; ++i)
        out[(size_t)(v0 + g * 4 + i) * 16 + rc] = acc[i];

    // deterministic BN partials: per-channel sum & sumsq over this block's 64 voxels
    float s = acc[0] + acc[1] + acc[2] + acc[3];
    float q = acc[0] * acc[0] + acc[1] * acc[1] + acc[2] * acc[2] + acc[3] * acc[3];
    s += __shfl_xor(s, 16);  s += __shfl_xor(s, 32);
    q += __shfl_xor(q, 16);  q += __shfl_xor(q, 32);

    if (lane < 16) {
        red[wv * 32 + rc]      = s;
        red[wv * 32 + 16 + rc] = q;
    }
    __syncthreads();
    if (threadIdx.x < 32) {
        float v = red[threadIdx.x] + red[32 + threadIdx.x] +
                  red[64 + threadIdx.x] + red[96 + threadIdx.x];
        partials[(size_t)threadIdx.x * NBLK + blockIdx.x] = v;
    }
}

__global__ __launch_bounds__(256) void reduce_k(const float* __restrict__ partials,
                                                float* __restrict__ S) {
    int c = blockIdx.x;  // 0..31 (16 sums, 16 sumsqs)
    float s = 0.f;
    for (int i = threadIdx.x; i < NBLK; i += 256) s += partials[(size_t)c * NBLK + i];
    __shared__ float red[256];
    red[threadIdx.x] = s;
    __syncthreads();
#pragma unroll
    for (int off = 128; off > 0; off >>= 1) {
        if (threadIdx.x < off) red[threadIdx.x] += red[threadIdx.x + off];
        __syncthreads();
    }
    if (threadIdx.x == 0) S[c] = red[0];
}

// BN finalize fused; optional residual add, ReLU, f32 and/or bf16 outputs.
// NOTE: no __restrict__ on t/resid/f32out — they intentionally alias in some layers.
__global__ __launch_bounds__(256) void apply_k(const float* t,
                                               const float* __restrict__ S,
                                               const float* __restrict__ gamma,
                                               const float* __restrict__ beta,
                                               const float* resid,
                                               float* f32out,
                                               unsigned short* bfout) {
    int i = (blockIdx.x * 256 + threadIdx.x) * 4;
    int c = i & 12;
    f32x4 t4 = *reinterpret_cast<const f32x4*>(t + i);
    f32x4 r4 = {0.f, 0.f, 0.f, 0.f};
    if (resid) r4 = *reinterpret_cast<const f32x4*>(resid + i);
    const float inv = 1.0f / (float)N_TOT;
    f32x4 val;
#pragma unroll
    for (int j = 0; j < 4; ++j) {
        float m   = S[c + j] * inv;
        float var = S[16 + c + j] * inv - m * m;
        float sc  = gamma[c + j] * rsqrtf(var + 1e-3f);
        float sh  = beta[c + j] - m * sc;
        val[j] = fmaxf(t4[j] * sc + sh + r4[j], 0.f);
    }
    if (f32out) *reinterpret_cast<f32x4*>(f32out + i) = val;
    if (bfout) {
        us4 o = { f2bf(val[0]), f2bf(val[1]), f2bf(val[2]), f2bf(val[3]) };
        *reinterpret_cast<us4*>(bfout + i) = o;
    }
}

extern "C" void kernel_launch(void* const* d_in, const int* in_sizes, int n_in,
                              void* d_out, int out_size, void* d_ws, size_t ws_size,
                              hipStream_t stream) {
    const float* vf   = (const float*)d_in[0];
    const int*   nbr  = (const int*)  d_in[1];
    const float* w_in = (const float*)d_in[2];
    const float* g_in = (const float*)d_in[3];
    const float* b_in = (const float*)d_in[4];
    const float* wbs  = (const float*)d_in[5];
    const float* gs   = (const float*)d_in[6];
    const float* bs   = (const float*)d_in[7];
    float* out = (float*)d_out;

    char* ws = (char*)d_ws;
    size_t off = 0;
    auto alloc = [&](size_t b) { char* p = ws + off; off += (b + 255) & ~(size_t)255; return p; };
    unsigned short* wfrag = (unsigned short*)alloc((size_t)5 * 14 * 64 * 8 * 2);
    unsigned short* xb    = (unsigned short*)alloc((size_t)NELEM * 2);  // bf16 features (x)
    unsigned short* ob    = (unsigned short*)alloc((size_t)NELEM * 2);  // bf16 features (o)
    float*          xf    = (float*)alloc((size_t)NELEM * 4);           // f32 residual copy
    float*          part  = (float*)alloc((size_t)32 * NBLK * 4);
    float*          S     = (float*)alloc(32 * 4);
    size_t idx_bytes = (size_t)NWAVE * 32 * 16 * 4;                     // 51.2 MB
    int*   idxpk = nullptr;
    if (off + idx_bytes + 256 <= ws_size) idxpk = (int*)alloc(idx_bytes);

    const int FR = 14 * 64 * 8;  // ushorts per layer of wfrag

    wfrag_k<<<70, 64, 0, stream>>>(w_in, wbs, wfrag);
    cvt_k<<<6250, 256, 0, stream>>>(vf, xb);
    if (idxpk) prep_k<<<NWAVE * 2, 256, 0, stream>>>(nbr, idxpk);

    // L0: x0 = relu(bn(conv(vf)))                 -> xb (bf16) + xf (f32)
    conv_k<<<NBLK, 256, 0, stream>>>(xb, nbr, idxpk, wfrag, out, part);
    reduce_k<<<32, 256, 0, stream>>>(part, S);
    apply_k<<<6250, 256, 0, stream>>>(out, S, g_in, b_in, nullptr, xf, xb);

    // L1: o = relu(bn(conv(x0)))                  -> ob
    conv_k<<<NBLK, 256, 0, stream>>>(xb, nbr, idxpk, wfrag + FR, out, part);
    reduce_k<<<32, 256, 0, stream>>>(part, S);
    apply_k<<<6250, 256, 0, stream>>>(out, S, gs + 0, bs + 0, nullptr, nullptr, ob);

    // L2: x1 = relu(bn(conv(o)) + x0)             -> xb + xf (in place)
    conv_k<<<NBLK, 256, 0, stream>>>(ob, nbr, idxpk, wfrag + 2 * FR, out, part);
    reduce_k<<<32, 256, 0, stream>>>(part, S);
    apply_k<<<6250, 256, 0, stream>>>(out, S, gs + 16, bs + 16, xf, xf, xb);

    // L3: o = relu(bn(conv(x1)))                  -> ob
    conv_k<<<NBLK, 256, 0, stream>>>(xb, nbr, idxpk, wfrag + 3 * FR, out, part);
    reduce_k<<<32, 256, 0, stream>>>(part, S);
    apply_k<<<6250, 256, 0, stream>>>(out, S, gs + 32, bs + 32, nullptr, nullptr, ob);

    // L4: out = relu(bn(conv(o)) + x1)            -> d_out (f32, in place)
    conv_k<<<NBLK, 256, 0, stream>>>(ob, nbr, idxpk, wfrag + 4 * FR, out, part);
    reduce_k<<<32, 256, 0, stream>>>(part, S);
    apply_k<<<6250, 256, 0, stream>>>(out, S, gs + 48, bs + 48, xf, out, nullptr);
}

// Round 3
// 229.494 us; speedup vs baseline: 1.4170x; 1.4170x over previous
//
#include <hip/hip_runtime.h>

#define N_TOT 400000
#define NBLK  6250          // N_TOT / 64 voxels per block
#define NELEM (N_TOT * 16)

typedef __attribute__((ext_vector_type(8))) short short8;
typedef __attribute__((ext_vector_type(4))) float f32x4;
typedef __attribute__((ext_vector_type(4))) unsigned short us4;

__device__ __forceinline__ unsigned short f2bf(float x) {
    unsigned int u = __float_as_uint(x);
    u += 0x7FFFu + ((u >> 16) & 1u);       // round-to-nearest-even
    return (unsigned short)(u >> 16);
}

// Build bf16 B-fragments for all 5 layers x 14 k-pairs, and zero the pad voxel
// (index N_TOT) in both bf16 feature buffers (invalid gathers land there).
// mfma_f32_16x16x32_bf16 B layout: lane l holds B[k=8*(l>>4)+j][col=l&15].
__global__ __launch_bounds__(64) void wfrag_k(const float* __restrict__ w_in,
                                              const float* __restrict__ wbs,
                                              unsigned short* __restrict__ wfrag,
                                              unsigned short* __restrict__ xb,
                                              unsigned short* __restrict__ ob) {
    if (blockIdx.x == 0 && threadIdx.x < 8) {
        us4 z = {0, 0, 0, 0};
        unsigned short* base = (threadIdx.x < 4) ? xb : ob;
        reinterpret_cast<us4*>(base + NELEM)[threadIdx.x & 3] = z;
    }
    int b = blockIdx.x;            // L*14 + p
    int L = b / 14, p = b % 14;
    int l = threadIdx.x;
    int g = l >> 4, col = l & 15;
    int k = 2 * p + (g >> 1);
    int cib = (g & 1) * 8;
    unsigned short v[8];
#pragma unroll
    for (int j = 0; j < 8; ++j) {
        float w = 0.f;
        if (k < 27) {
            int ci = cib + j;
            w = (L == 0) ? w_in[(k * 16 + ci) * 16 + col]
                         : wbs[(((L - 1) * 27 + k) * 16 + ci) * 16 + col];
        }
        v[j] = f2bf(w);
    }
    unsigned short* dst = wfrag + (size_t)(b * 64 + l) * 8;
#pragma unroll
    for (int j = 0; j < 8; ++j) dst[j] = v[j];
}

__global__ __launch_bounds__(256) void cvt_k(const float* __restrict__ in,
                                             unsigned short* __restrict__ out) {
    int i = (blockIdx.x * 256 + threadIdx.x) * 4;
    f32x4 v = *reinterpret_cast<const f32x4*>(in + i);
    us4 o = { f2bf(v[0]), f2bf(v[1]), f2bf(v[2]), f2bf(v[3]) };
    *reinterpret_cast<us4*>(out + i) = o;
}

// Gather-MFMA submanifold conv: 1 wave = 16 voxels, 4 waves/block.
// Straight-line: 14 idx loads -> 14 unconditional gathers (invalid -> zero
// voxel at N_TOT) -> sched_barrier -> 14 x (ds_read B + MFMA). All gathers
// stay in flight across the MFMA chain (a[14] = 56 VGPRs held live).
__global__ __launch_bounds__(256, 4) void conv_k(const unsigned short* __restrict__ feats,
                                                 const int* __restrict__ nbr,
                                                 const unsigned short* __restrict__ wfrag,
                                                 float* __restrict__ out,
                                                 float* __restrict__ partials) {
    __shared__ unsigned short wlds[14 * 64 * 8];   // 14336 B
    __shared__ float red[128];

    // cooperative wfrag stage: 14336 B = 896 x 16 B
    {
        const f32x4* src = reinterpret_cast<const f32x4*>(wfrag);
        f32x4* dst = reinterpret_cast<f32x4*>(wlds);
        for (int j = threadIdx.x; j < 896; j += 256) dst[j] = src[j];
    }
    __syncthreads();

    const int lane = threadIdx.x & 63;
    const int wv   = threadIdx.x >> 6;
    const int v0   = (blockIdx.x * 4 + wv) * 16;
    const int g    = lane >> 4;
    const int rc   = lane & 15;        // A-row / B-col
    const int half = (g & 1) * 8;      // which 8 input channels this lane loads
    const int ksel = g >> 1;           // which offset of the pair

    int idxs[14];
#pragma unroll
    for (int p = 0; p < 14; ++p) {
        int k = 2 * p + ksel;
        idxs[p] = (k < 27) ? nbr[(size_t)k * N_TOT + v0 + rc] : -1;
    }

    short8 a[14];
#pragma unroll
    for (int p = 0; p < 14; ++p) {
        int idx = idxs[p];
        int ci = idx < 0 ? N_TOT : idx;            // zero voxel for invalid
        a[p] = *reinterpret_cast<const short8*>(feats + ((size_t)ci << 4) + half);
    }
    __builtin_amdgcn_sched_barrier(0);             // keep all gathers issued first

    f32x4 acc = {0.f, 0.f, 0.f, 0.f};
#pragma unroll
    for (int p = 0; p < 14; ++p) {
        short8 b = *reinterpret_cast<const short8*>(&wlds[(p * 64 + lane) * 8]);
        acc = __builtin_amdgcn_mfma_f32_16x16x32_bf16(a[p], b, acc, 0, 0, 0);
    }

    // C/D layout: col = lane&15, row = (lane>>4)*4 + reg  [m89/m91 verified]
#pragma unroll
    for (int i = 0; i < 4; ++i)
        out[(size_t)(v0 + g * 4 + i) * 16 + rc] = acc[i];

    // deterministic BN partials: per-channel sum & sumsq over this block's 64 voxels
    float s = acc[0] + acc[1] + acc[2] + acc[3];
    float q = acc[0] * acc[0] + acc[1] * acc[1] + acc[2] * acc[2] + acc[3] * acc[3];
    s += __shfl_xor(s, 16);  s += __shfl_xor(s, 32);
    q += __shfl_xor(q, 16);  q += __shfl_xor(q, 32);

    if (lane < 16) {
        red[wv * 32 + rc]      = s;
        red[wv * 32 + 16 + rc] = q;
    }
    __syncthreads();
    if (threadIdx.x < 32) {
        float v = red[threadIdx.x] + red[32 + threadIdx.x] +
                  red[64 + threadIdx.x] + red[96 + threadIdx.x];
        partials[(size_t)threadIdx.x * NBLK + blockIdx.x] = v;
    }
}

__global__ __launch_bounds__(256) void reduce_k(const float* __restrict__ partials,
                                                float* __restrict__ S) {
    int c = blockIdx.x;  // 0..31 (16 sums, 16 sumsqs)
    float s = 0.f;
    for (int i = threadIdx.x; i < NBLK; i += 256) s += partials[(size_t)c * NBLK + i];
    __shared__ float red[256];
    red[threadIdx.x] = s;
    __syncthreads();
#pragma unroll
    for (int off = 128; off > 0; off >>= 1) {
        if (threadIdx.x < off) red[threadIdx.x] += red[threadIdx.x + off];
        __syncthreads();
    }
    if (threadIdx.x == 0) S[c] = red[0];
}

// BN finalize fused; optional residual add, ReLU, f32 and/or bf16 outputs.
// NOTE: no __restrict__ on t/resid/f32out — they intentionally alias in some layers.
__global__ __launch_bounds__(256) void apply_k(const float* t,
                                               const float* __restrict__ S,
                                               const float* __restrict__ gamma,
                                               const float* __restrict__ beta,
                                               const float* resid,
                                               float* f32out,
                                               unsigned short* bfout) {
    int i = (blockIdx.x * 256 + threadIdx.x) * 4;
    int c = i & 12;
    f32x4 t4 = *reinterpret_cast<const f32x4*>(t + i);
    f32x4 r4 = {0.f, 0.f, 0.f, 0.f};
    if (resid) r4 = *reinterpret_cast<const f32x4*>(resid + i);
    const float inv = 1.0f / (float)N_TOT;
    f32x4 val;
#pragma unroll
    for (int j = 0; j < 4; ++j) {
        float m   = S[c + j] * inv;
        float var = S[16 + c + j] * inv - m * m;
        float sc  = gamma[c + j] * rsqrtf(var + 1e-3f);
        float sh  = beta[c + j] - m * sc;
        val[j] = fmaxf(t4[j] * sc + sh + r4[j], 0.f);
    }
    if (f32out) *reinterpret_cast<f32x4*>(f32out + i) = val;
    if (bfout) {
        us4 o = { f2bf(val[0]), f2bf(val[1]), f2bf(val[2]), f2bf(val[3]) };
        *reinterpret_cast<us4*>(bfout + i) = o;
    }
}

extern "C" void kernel_launch(void* const* d_in, const int* in_sizes, int n_in,
                              void* d_out, int out_size, void* d_ws, size_t ws_size,
                              hipStream_t stream) {
    const float* vf   = (const float*)d_in[0];
    const int*   nbr  = (const int*)  d_in[1];
    const float* w_in = (const float*)d_in[2];
    const float* g_in = (const float*)d_in[3];
    const float* b_in = (const float*)d_in[4];
    const float* wbs  = (const float*)d_in[5];
    const float* gs   = (const float*)d_in[6];
    const float* bs   = (const float*)d_in[7];
    float* out = (float*)d_out;

    char* ws = (char*)d_ws;
    size_t off = 0;
    auto alloc = [&](size_t b) { char* p = ws + off; off += (b + 255) & ~(size_t)255; return p; };
    unsigned short* wfrag = (unsigned short*)alloc((size_t)5 * 14 * 64 * 8 * 2);
    unsigned short* xb    = (unsigned short*)alloc((size_t)(NELEM + 16) * 2);  // bf16 x (+zero voxel)
    unsigned short* ob    = (unsigned short*)alloc((size_t)(NELEM + 16) * 2);  // bf16 o (+zero voxel)
    float*          xf    = (float*)alloc((size_t)NELEM * 4);                  // f32 residual copy
    float*          part  = (float*)alloc((size_t)32 * NBLK * 4);
    float*          S     = (float*)alloc(32 * 4);

    const int FR = 14 * 64 * 8;  // ushorts per layer of wfrag

    wfrag_k<<<70, 64, 0, stream>>>(w_in, wbs, wfrag, xb, ob);
    cvt_k<<<6250, 256, 0, stream>>>(vf, xb);

    // L0: x0 = relu(bn(conv(vf)))                 -> xb (bf16) + xf (f32)
    conv_k<<<NBLK, 256, 0, stream>>>(xb, nbr, wfrag, out, part);
    reduce_k<<<32, 256, 0, stream>>>(part, S);
    apply_k<<<6250, 256, 0, stream>>>(out, S, g_in, b_in, nullptr, xf, xb);

    // L1: o = relu(bn(conv(x0)))                  -> ob
    conv_k<<<NBLK, 256, 0, stream>>>(xb, nbr, wfrag + FR, out, part);
    reduce_k<<<32, 256, 0, stream>>>(part, S);
    apply_k<<<6250, 256, 0, stream>>>(out, S, gs + 0, bs + 0, nullptr, nullptr, ob);

    // L2: x1 = relu(bn(conv(o)) + x0)             -> xb + xf (in place)
    conv_k<<<NBLK, 256, 0, stream>>>(ob, nbr, wfrag + 2 * FR, out, part);
    reduce_k<<<32, 256, 0, stream>>>(part, S);
    apply_k<<<6250, 256, 0, stream>>>(out, S, gs + 16, bs + 16, xf, xf, xb);

    // L3: o = relu(bn(conv(x1)))                  -> ob
    conv_k<<<NBLK, 256, 0, stream>>>(xb, nbr, wfrag + 3 * FR, out, part);
    reduce_k<<<32, 256, 0, stream>>>(part, S);
    apply_k<<<6250, 256, 0, stream>>>(out, S, gs + 32, bs + 32, nullptr, nullptr, ob);

    // L4: out = relu(bn(conv(o)) + x1)            -> d_out (f32, in place)
    conv_k<<<NBLK, 256, 0, stream>>>(ob, nbr, wfrag + 4 * FR, out, part);
    reduce_k<<<32, 256, 0, stream>>>(part, S);
    apply_k<<<6250, 256, 0, stream>>>(out, S, gs + 48, bs + 48, xf, out, nullptr);
}

// Round 4
// 197.343 us; speedup vs baseline: 1.6479x; 1.1629x over previous
//
#include <hip/hip_runtime.h>

#define N_TOT  400000
#define NTILE  25000        // N_TOT / 16 voxels per tile
#define NELEM  (N_TOT * 16)
#define CBLK   768          // persistent conv blocks
#define GSTRIDE (CBLK * 4)  // waves in grid

typedef __attribute__((ext_vector_type(8))) short short8;
typedef __attribute__((ext_vector_type(4))) float f32x4;
typedef __attribute__((ext_vector_type(4))) unsigned short us4;

__device__ __forceinline__ unsigned short f2bf(float x) {
    unsigned int u = __float_as_uint(x);
    u += 0x7FFFu + ((u >> 16) & 1u);       // round-to-nearest-even
    return (unsigned short)(u >> 16);
}

// Build bf16 B-fragments for all 5 layers x 14 k-pairs, and zero the pad voxel
// (index N_TOT) in both bf16 feature buffers (invalid gathers land there).
// mfma_f32_16x16x32_bf16 B layout: lane l holds B[k=8*(l>>4)+j][col=l&15].
__global__ __launch_bounds__(64) void wfrag_k(const float* __restrict__ w_in,
                                              const float* __restrict__ wbs,
                                              unsigned short* __restrict__ wfrag,
                                              unsigned short* __restrict__ xb,
                                              unsigned short* __restrict__ ob) {
    if (blockIdx.x == 0 && threadIdx.x < 8) {
        us4 z = {0, 0, 0, 0};
        unsigned short* base = (threadIdx.x < 4) ? xb : ob;
        reinterpret_cast<us4*>(base + NELEM)[threadIdx.x & 3] = z;
    }
    int b = blockIdx.x;            // L*14 + p
    int L = b / 14, p = b % 14;
    int l = threadIdx.x;
    int g = l >> 4, col = l & 15;
    int k = 2 * p + (g >> 1);
    int cib = (g & 1) * 8;
    unsigned short v[8];
#pragma unroll
    for (int j = 0; j < 8; ++j) {
        float w = 0.f;
        if (k < 27) {
            int ci = cib + j;
            w = (L == 0) ? w_in[(k * 16 + ci) * 16 + col]
                         : wbs[(((L - 1) * 27 + k) * 16 + ci) * 16 + col];
        }
        v[j] = f2bf(w);
    }
    unsigned short* dst = wfrag + (size_t)(b * 64 + l) * 8;
#pragma unroll
    for (int j = 0; j < 8; ++j) dst[j] = v[j];
}

__global__ __launch_bounds__(256) void cvt_k(const float* __restrict__ in,
                                             unsigned short* __restrict__ out) {
    int i = (blockIdx.x * 256 + threadIdx.x) * 4;
    f32x4 v = *reinterpret_cast<const f32x4*>(in + i);
    us4 o = { f2bf(v[0]), f2bf(v[1]), f2bf(v[2]), f2bf(v[3]) };
    *reinterpret_cast<us4*>(out + i) = o;
}

// Persistent gather-MFMA conv. 3072 waves, each grid-strides over ~8 16-voxel
// tiles with a 2-deep register pipeline: idx+gathers of tile t+1 issue before
// the MFMA chain of tile t. wfrag staged to LDS once per block. Center offset
// (k=13) is the identity -> no idx load. Invalid neighbors -> zero voxel N_TOT.
#define PRE(A, tt)                                                              \
  {                                                                             \
    const int vv = (tt) * 16;                                                   \
    int idxs[14];                                                               \
    _Pragma("unroll")                                                           \
    for (int p = 0; p < 14; ++p) {                                              \
      int k = 2 * p + ksel;                                                     \
      if (k == 13)      idxs[p] = vv + rc;                                      \
      else if (k < 27)  idxs[p] = nbr[(size_t)k * N_TOT + vv + rc];             \
      else              idxs[p] = -1;                                           \
    }                                                                           \
    _Pragma("unroll")                                                           \
    for (int p = 0; p < 14; ++p) {                                              \
      int ci = idxs[p] < 0 ? N_TOT : idxs[p];                                   \
      A[p] = *reinterpret_cast<const short8*>(feats + ((size_t)ci << 4) + half);\
    }                                                                           \
  }

#define CMP(A, tt)                                                              \
  {                                                                             \
    f32x4 acc = {0.f, 0.f, 0.f, 0.f};                                           \
    _Pragma("unroll")                                                           \
    for (int p = 0; p < 14; ++p) {                                              \
      short8 bf = *reinterpret_cast<const short8*>(&wlds[(p * 64 + lane) * 8]); \
      acc = __builtin_amdgcn_mfma_f32_16x16x32_bf16(A[p], bf, acc, 0, 0, 0);    \
    }                                                                           \
    const int vv = (tt) * 16;                                                   \
    _Pragma("unroll")                                                           \
    for (int i = 0; i < 4; ++i)                                                 \
      out[(size_t)(vv + g * 4 + i) * 16 + rc] = acc[i];                         \
    s_acc += acc[0] + acc[1] + acc[2] + acc[3];                                 \
    q_acc += acc[0]*acc[0] + acc[1]*acc[1] + acc[2]*acc[2] + acc[3]*acc[3];     \
  }

__global__ __launch_bounds__(256, 3) void conv_k(const unsigned short* __restrict__ feats,
                                                 const int* __restrict__ nbr,
                                                 const unsigned short* __restrict__ wfrag,
                                                 float* __restrict__ out,
                                                 float* __restrict__ partials) {
    __shared__ unsigned short wlds[14 * 64 * 8];   // 14336 B
    __shared__ float red[128];

    {   // cooperative wfrag stage: 14336 B = 896 x 16 B (once per block)
        const f32x4* src = reinterpret_cast<const f32x4*>(wfrag);
        f32x4* dst = reinterpret_cast<f32x4*>(wlds);
        for (int j = threadIdx.x; j < 896; j += 256) dst[j] = src[j];
    }
    __syncthreads();

    const int lane = threadIdx.x & 63;
    const int wv   = threadIdx.x >> 6;
    const int g    = lane >> 4;
    const int rc   = lane & 15;        // A-row / B-col
    const int half = (g & 1) * 8;      // which 8 input channels this lane loads
    const int ksel = g >> 1;           // which offset of the pair

    float s_acc = 0.f, q_acc = 0.f;
    int t = blockIdx.x * 4 + wv;       // first tile for this wave

    short8 A0[14], A1[14];
    PRE(A0, t);
    for (;;) {
        int t1 = t + GSTRIDE;
        if (t1 < NTILE) PRE(A1, t1);
        __builtin_amdgcn_sched_barrier(0);
        CMP(A0, t);
        if (t1 >= NTILE) break;
        t = t1;
        int t2 = t + GSTRIDE;
        if (t2 < NTILE) PRE(A0, t2);
        __builtin_amdgcn_sched_barrier(0);
        CMP(A1, t);
        if (t2 >= NTILE) break;
        t = t2;
    }

    // BN partials: per-channel sum & sumsq over all tiles this block touched
    s_acc += __shfl_xor(s_acc, 16);  s_acc += __shfl_xor(s_acc, 32);
    q_acc += __shfl_xor(q_acc, 16);  q_acc += __shfl_xor(q_acc, 32);
    if (lane < 16) {
        red[wv * 32 + rc]      = s_acc;
        red[wv * 32 + 16 + rc] = q_acc;
    }
    __syncthreads();
    if (threadIdx.x < 32) {
        float v = red[threadIdx.x] + red[32 + threadIdx.x] +
                  red[64 + threadIdx.x] + red[96 + threadIdx.x];
        partials[(size_t)threadIdx.x * CBLK + blockIdx.x] = v;
    }
}

__global__ __launch_bounds__(256) void reduce_k(const float* __restrict__ partials,
                                                float* __restrict__ S) {
    int c = blockIdx.x;  // 0..31 (16 sums, 16 sumsqs)
    float s = 0.f;
    for (int i = threadIdx.x; i < CBLK; i += 256) s += partials[(size_t)c * CBLK + i];
    __shared__ float red[256];
    red[threadIdx.x] = s;
    __syncthreads();
#pragma unroll
    for (int off = 128; off > 0; off >>= 1) {
        if (threadIdx.x < off) red[threadIdx.x] += red[threadIdx.x + off];
        __syncthreads();
    }
    if (threadIdx.x == 0) S[c] = red[0];
}

// BN finalize fused; optional residual add, ReLU, f32 and/or bf16 outputs.
// NOTE: no __restrict__ on t/resid/f32out — they intentionally alias in some layers.
__global__ __launch_bounds__(256) void apply_k(const float* t,
                                               const float* __restrict__ S,
                                               const float* __restrict__ gamma,
                                               const float* __restrict__ beta,
                                               const float* resid,
                                               float* f32out,
                                               unsigned short* bfout) {
    int i = (blockIdx.x * 256 + threadIdx.x) * 4;
    int c = i & 12;
    f32x4 t4 = *reinterpret_cast<const f32x4*>(t + i);
    f32x4 r4 = {0.f, 0.f, 0.f, 0.f};
    if (resid) r4 = *reinterpret_cast<const f32x4*>(resid + i);
    const float inv = 1.0f / (float)N_TOT;
    f32x4 val;
#pragma unroll
    for (int j = 0; j < 4; ++j) {
        float m   = S[c + j] * inv;
        float var = S[16 + c + j] * inv - m * m;
        float sc  = gamma[c + j] * rsqrtf(var + 1e-3f);
        float sh  = beta[c + j] - m * sc;
        val[j] = fmaxf(t4[j] * sc + sh + r4[j], 0.f);
    }
    if (f32out) *reinterpret_cast<f32x4*>(f32out + i) = val;
    if (bfout) {
        us4 o = { f2bf(val[0]), f2bf(val[1]), f2bf(val[2]), f2bf(val[3]) };
        *reinterpret_cast<us4*>(bfout + i) = o;
    }
}

extern "C" void kernel_launch(void* const* d_in, const int* in_sizes, int n_in,
                              void* d_out, int out_size, void* d_ws, size_t ws_size,
                              hipStream_t stream) {
    const float* vf   = (const float*)d_in[0];
    const int*   nbr  = (const int*)  d_in[1];
    const float* w_in = (const float*)d_in[2];
    const float* g_in = (const float*)d_in[3];
    const float* b_in = (const float*)d_in[4];
    const float* wbs  = (const float*)d_in[5];
    const float* gs   = (const float*)d_in[6];
    const float* bs   = (const float*)d_in[7];
    float* out = (float*)d_out;

    char* ws = (char*)d_ws;
    size_t off = 0;
    auto alloc = [&](size_t b) { char* p = ws + off; off += (b + 255) & ~(size_t)255; return p; };
    unsigned short* wfrag = (unsigned short*)alloc((size_t)5 * 14 * 64 * 8 * 2);
    unsigned short* xb    = (unsigned short*)alloc((size_t)(NELEM + 16) * 2);  // bf16 x (+zero voxel)
    unsigned short* ob    = (unsigned short*)alloc((size_t)(NELEM + 16) * 2);  // bf16 o (+zero voxel)
    float*          xf    = (float*)alloc((size_t)NELEM * 4);                  // f32 residual copy
    float*          part  = (float*)alloc((size_t)32 * CBLK * 4);
    float*          S     = (float*)alloc(32 * 4);

    const int FR = 14 * 64 * 8;  // ushorts per layer of wfrag

    wfrag_k<<<70, 64, 0, stream>>>(w_in, wbs, wfrag, xb, ob);
    cvt_k<<<6250, 256, 0, stream>>>(vf, xb);

    // L0: x0 = relu(bn(conv(vf)))                 -> xb (bf16) + xf (f32)
    conv_k<<<CBLK, 256, 0, stream>>>(xb, nbr, wfrag, out, part);
    reduce_k<<<32, 256, 0, stream>>>(part, S);
    apply_k<<<6250, 256, 0, stream>>>(out, S, g_in, b_in, nullptr, xf, xb);

    // L1: o = relu(bn(conv(x0)))                  -> ob
    conv_k<<<CBLK, 256, 0, stream>>>(xb, nbr, wfrag + FR, out, part);
    reduce_k<<<32, 256, 0, stream>>>(part, S);
    apply_k<<<6250, 256, 0, stream>>>(out, S, gs + 0, bs + 0, nullptr, nullptr, ob);

    // L2: x1 = relu(bn(conv(o)) + x0)             -> xb + xf (in place)
    conv_k<<<CBLK, 256, 0, stream>>>(ob, nbr, wfrag + 2 * FR, out, part);
    reduce_k<<<32, 256, 0, stream>>>(part, S);
    apply_k<<<6250, 256, 0, stream>>>(out, S, gs + 16, bs + 16, xf, xf, xb);

    // L3: o = relu(bn(conv(x1)))                  -> ob
    conv_k<<<CBLK, 256, 0, stream>>>(xb, nbr, wfrag + 3 * FR, out, part);
    reduce_k<<<32, 256, 0, stream>>>(part, S);
    apply_k<<<6250, 256, 0, stream>>>(out, S, gs + 32, bs + 32, nullptr, nullptr, ob);

    // L4: out = relu(bn(conv(o)) + x1)            -> d_out (f32, in place)
    conv_k<<<CBLK, 256, 0, stream>>>(ob, nbr, wfrag + 4 * FR, out, part);
    reduce_k<<<32, 256, 0, stream>>>(part, S);
    apply_k<<<6250, 256, 0, stream>>>(out, S, gs + 48, bs + 48, xf, out, nullptr);
}

// Round 5
// 177.757 us; speedup vs baseline: 1.8295x; 1.1102x over previous
//
#include <hip/hip_runtime.h>

#define N_TOT  400000
#define NTILE  25000        // N_TOT / 16 voxels per tile
#define NELEM  (N_TOT * 16)
#define CBLK   512          // persistent conv blocks (2 per CU)
#define GSTRIDE (CBLK * 4)  // waves in grid

typedef __attribute__((ext_vector_type(8))) short short8;
typedef __attribute__((ext_vector_type(4))) float f32x4;
typedef __attribute__((ext_vector_type(4))) unsigned short us4;

__device__ __forceinline__ unsigned short f2bf(float x) {
    unsigned int u = __float_as_uint(x);
    u += 0x7FFFu + ((u >> 16) & 1u);       // round-to-nearest-even
    return (unsigned short)(u >> 16);
}
__device__ __forceinline__ float bf2f(unsigned short h) {
    return __uint_as_float(((unsigned int)h) << 16);
}

// Build bf16 B-fragments for all 5 layers x 14 k-pairs, and zero the pad voxel
// (index N_TOT) in both bf16 gather buffers (invalid neighbors land there).
// mfma_f32_16x16x32_bf16 B layout: lane l holds B[k=8*(l>>4)+j][col=l&15].
__global__ __launch_bounds__(64) void wfrag_k(const float* __restrict__ w_in,
                                              const float* __restrict__ wbs,
                                              unsigned short* __restrict__ wfrag,
                                              unsigned short* __restrict__ xb,
                                              unsigned short* __restrict__ ob) {
    if (blockIdx.x == 0 && threadIdx.x < 8) {
        us4 z = {0, 0, 0, 0};
        unsigned short* base = (threadIdx.x < 4) ? xb : ob;
        reinterpret_cast<us4*>(base + NELEM)[threadIdx.x & 3] = z;
    }
    int b = blockIdx.x;            // L*14 + p
    int L = b / 14, p = b % 14;
    int l = threadIdx.x;
    int g = l >> 4, col = l & 15;
    int k = 2 * p + (g >> 1);
    int cib = (g & 1) * 8;
    unsigned short v[8];
#pragma unroll
    for (int j = 0; j < 8; ++j) {
        float w = 0.f;
        if (k < 27) {
            int ci = cib + j;
            w = (L == 0) ? w_in[(k * 16 + ci) * 16 + col]
                         : wbs[(((L - 1) * 27 + k) * 16 + ci) * 16 + col];
        }
        v[j] = f2bf(w);
    }
    unsigned short* dst = wfrag + (size_t)(b * 64 + l) * 8;
#pragma unroll
    for (int j = 0; j < 8; ++j) dst[j] = v[j];
}

__global__ __launch_bounds__(256) void cvt_k(const float* __restrict__ in,
                                             unsigned short* __restrict__ out) {
    int i = (blockIdx.x * 256 + threadIdx.x) * 8;
    f32x4 a = *reinterpret_cast<const f32x4*>(in + i);
    f32x4 b = *reinterpret_cast<const f32x4*>(in + i + 4);
    short8 o = { (short)f2bf(a[0]), (short)f2bf(a[1]), (short)f2bf(a[2]), (short)f2bf(a[3]),
                 (short)f2bf(b[0]), (short)f2bf(b[1]), (short)f2bf(b[2]), (short)f2bf(b[3]) };
    *reinterpret_cast<short8*>(out + i) = o;
}

// Persistent gather-MFMA conv, 3-stage decoupled pipeline per wave:
//   idx loads for tile t+2S | gathers for tile t+S | MFMA+store of tile t.
// wfrag staged to LDS once per block. Center offset (k=13) = identity (no load).
// Invalid neighbors gather the zero voxel at N_TOT. Raw output stored bf16.
#define IDX(I, tt)                                                              \
  {                                                                             \
    const int vv = (tt) * 16;                                                   \
    _Pragma("unroll")                                                           \
    for (int p = 0; p < 14; ++p) {                                              \
      int k = 2 * p + ksel;                                                     \
      if (k == 13)      I[p] = vv + rc;                                         \
      else if (k < 27)  I[p] = nbr[(size_t)k * N_TOT + vv + rc];                \
      else              I[p] = -1;                                              \
    }                                                                           \
  }

#define GAT(A, I)                                                               \
  {                                                                             \
    _Pragma("unroll")                                                           \
    for (int p = 0; p < 14; ++p) {                                              \
      int ci = I[p] < 0 ? N_TOT : I[p];                                         \
      A[p] = *reinterpret_cast<const short8*>(feats + ((size_t)ci << 4) + half);\
    }                                                                           \
  }

#define CMP(A, tt)                                                              \
  {                                                                             \
    f32x4 acc = {0.f, 0.f, 0.f, 0.f};                                           \
    _Pragma("unroll")                                                           \
    for (int p = 0; p < 14; ++p) {                                              \
      short8 bf = *reinterpret_cast<const short8*>(&wlds[(p * 64 + lane) * 8]); \
      acc = __builtin_amdgcn_mfma_f32_16x16x32_bf16(A[p], bf, acc, 0, 0, 0);    \
    }                                                                           \
    const int vv = (tt) * 16;                                                   \
    _Pragma("unroll")                                                           \
    for (int i = 0; i < 4; ++i)                                                 \
      raw[(size_t)(vv + g * 4 + i) * 16 + rc] = f2bf(acc[i]);                   \
    s_acc += acc[0] + acc[1] + acc[2] + acc[3];                                 \
    q_acc += acc[0]*acc[0] + acc[1]*acc[1] + acc[2]*acc[2] + acc[3]*acc[3];     \
  }

__global__ __launch_bounds__(256, 2) void conv_k(const unsigned short* __restrict__ feats,
                                                 const int* __restrict__ nbr,
                                                 const unsigned short* __restrict__ wfrag,
                                                 unsigned short* __restrict__ raw,
                                                 float* __restrict__ partials) {
    __shared__ unsigned short wlds[14 * 64 * 8];   // 14336 B
    __shared__ float red[128];

    {   // cooperative wfrag stage: 14336 B = 896 x 16 B (once per block)
        const f32x4* src = reinterpret_cast<const f32x4*>(wfrag);
        f32x4* dst = reinterpret_cast<f32x4*>(wlds);
        for (int j = threadIdx.x; j < 896; j += 256) dst[j] = src[j];
    }
    __syncthreads();

    const int lane = threadIdx.x & 63;
    const int wv   = threadIdx.x >> 6;
    const int g    = lane >> 4;
    const int rc   = lane & 15;        // A-row / B-col
    const int half = (g & 1) * 8;      // which 8 input channels this lane loads
    const int ksel = g >> 1;           // which offset of the pair

    float s_acc = 0.f, q_acc = 0.f;

    int I0[14], I1[14];
    short8 A0[14], A1[14];

    int t0 = blockIdx.x * 4 + wv;
    IDX(I0, t0);
    GAT(A0, I0);                       // one exposed stall at prologue
    int t1 = t0 + GSTRIDE;
    if (t1 < NTILE) IDX(I1, t1);

    for (;;) {
        // invariant: A0 in flight for t0; I1 in flight/arrived for t1
        int t2 = t0 + 2 * GSTRIDE;
        if (t2 < NTILE) IDX(I0, t2);
        if (t1 < NTILE) GAT(A1, I1);
        __builtin_amdgcn_sched_barrier(0);
        CMP(A0, t0);
        if (t1 >= NTILE) break;

        int t3 = t1 + 2 * GSTRIDE;
        if (t3 < NTILE) IDX(I1, t3);
        if (t2 < NTILE) GAT(A0, I0);
        __builtin_amdgcn_sched_barrier(0);
        CMP(A1, t1);
        if (t2 >= NTILE) break;

        t0 = t2;
        t1 = t2 + GSTRIDE;
    }

    // BN partials: per-channel sum & sumsq over all tiles this block touched
    s_acc += __shfl_xor(s_acc, 16);  s_acc += __shfl_xor(s_acc, 32);
    q_acc += __shfl_xor(q_acc, 16);  q_acc += __shfl_xor(q_acc, 32);
    if (lane < 16) {
        red[wv * 32 + rc]      = s_acc;
        red[wv * 32 + 16 + rc] = q_acc;
    }
    __syncthreads();
    if (threadIdx.x < 32) {
        float v = red[threadIdx.x] + red[32 + threadIdx.x] +
                  red[64 + threadIdx.x] + red[96 + threadIdx.x];
        partials[(size_t)threadIdx.x * CBLK + blockIdx.x] = v;
    }
}

__global__ __launch_bounds__(256) void reduce_k(const float* __restrict__ partials,
                                                float* __restrict__ S) {
    int c = blockIdx.x;  // 0..31 (16 sums, 16 sumsqs)
    float s = 0.f;
    for (int i = threadIdx.x; i < CBLK; i += 256) s += partials[(size_t)c * CBLK + i];
    __shared__ float red[256];
    red[threadIdx.x] = s;
    __syncthreads();
#pragma unroll
    for (int off = 128; off > 0; off >>= 1) {
        if (threadIdx.x < off) red[threadIdx.x] += red[threadIdx.x + off];
        __syncthreads();
    }
    if (threadIdx.x == 0) S[c] = red[0];
}

// BN finalize fused; reads raw bf16 conv output, optional bf16 residual,
// writes bf16 feature buffer and/or f32 final output. 8 elems/thread.
__global__ __launch_bounds__(256) void apply_k(const unsigned short* __restrict__ raw,
                                               const float* __restrict__ S,
                                               const float* __restrict__ gamma,
                                               const float* __restrict__ beta,
                                               const unsigned short* residb,
                                               unsigned short* bfout,
                                               float* f32out) {
    int i = (blockIdx.x * 256 + threadIdx.x) * 8;
    int c0 = i & 8;                    // channels c0..c0+7
    short8 r8 = *reinterpret_cast<const short8*>(raw + i);
    float res[8] = {0, 0, 0, 0, 0, 0, 0, 0};
    if (residb) {
        short8 x8 = *reinterpret_cast<const short8*>(residb + i);
#pragma unroll
        for (int j = 0; j < 8; ++j) res[j] = bf2f((unsigned short)x8[j]);
    }
    const float inv = 1.0f / (float)N_TOT;
    float val[8];
#pragma unroll
    for (int j = 0; j < 8; ++j) {
        int c = c0 + j;
        float m   = S[c] * inv;
        float var = S[16 + c] * inv - m * m;
        float sc  = gamma[c] * rsqrtf(var + 1e-3f);
        float sh  = beta[c] - m * sc;
        val[j] = fmaxf(bf2f((unsigned short)r8[j]) * sc + sh + res[j], 0.f);
    }
    if (bfout) {
        short8 o = { (short)f2bf(val[0]), (short)f2bf(val[1]), (short)f2bf(val[2]), (short)f2bf(val[3]),
                     (short)f2bf(val[4]), (short)f2bf(val[5]), (short)f2bf(val[6]), (short)f2bf(val[7]) };
        *reinterpret_cast<short8*>(bfout + i) = o;
    }
    if (f32out) {
        f32x4 lo = { val[0], val[1], val[2], val[3] };
        f32x4 hi = { val[4], val[5], val[6], val[7] };
        *reinterpret_cast<f32x4*>(f32out + i)     = lo;
        *reinterpret_cast<f32x4*>(f32out + i + 4) = hi;
    }
}

extern "C" void kernel_launch(void* const* d_in, const int* in_sizes, int n_in,
                              void* d_out, int out_size, void* d_ws, size_t ws_size,
                              hipStream_t stream) {
    const float* vf   = (const float*)d_in[0];
    const int*   nbr  = (const int*)  d_in[1];
    const float* w_in = (const float*)d_in[2];
    const float* g_in = (const float*)d_in[3];
    const float* b_in = (const float*)d_in[4];
    const float* wbs  = (const float*)d_in[5];
    const float* gs   = (const float*)d_in[6];
    const float* bs   = (const float*)d_in[7];
    float* out = (float*)d_out;

    char* ws = (char*)d_ws;
    size_t off = 0;
    auto alloc = [&](size_t b) { char* p = ws + off; off += (b + 255) & ~(size_t)255; return p; };
    unsigned short* wfrag = (unsigned short*)alloc((size_t)5 * 14 * 64 * 8 * 2);
    unsigned short* xb    = (unsigned short*)alloc((size_t)(NELEM + 16) * 2);  // bf16 x (+zero voxel)
    unsigned short* ob    = (unsigned short*)alloc((size_t)(NELEM + 16) * 2);  // bf16 o (+zero voxel)
    unsigned short* rb    = (unsigned short*)alloc((size_t)NELEM * 2);         // bf16 raw conv out
    float*          part  = (float*)alloc((size_t)32 * CBLK * 4);
    float*          S     = (float*)alloc(32 * 4);

    const int FR = 14 * 64 * 8;  // ushorts per layer of wfrag

    wfrag_k<<<70, 64, 0, stream>>>(w_in, wbs, wfrag, xb, ob);
    cvt_k<<<3125, 256, 0, stream>>>(vf, xb);

    // L0: x0 = relu(bn(conv(vf)))                 -> xb
    conv_k<<<CBLK, 256, 0, stream>>>(xb, nbr, wfrag, rb, part);
    reduce_k<<<32, 256, 0, stream>>>(part, S);
    apply_k<<<3125, 256, 0, stream>>>(rb, S, g_in, b_in, nullptr, xb, nullptr);

    // L1: o = relu(bn(conv(x0)))                  -> ob
    conv_k<<<CBLK, 256, 0, stream>>>(xb, nbr, wfrag + FR, rb, part);
    reduce_k<<<32, 256, 0, stream>>>(part, S);
    apply_k<<<3125, 256, 0, stream>>>(rb, S, gs + 0, bs + 0, nullptr, ob, nullptr);

    // L2: x1 = relu(bn(conv(o)) + x0)             -> xb (in place resid)
    conv_k<<<CBLK, 256, 0, stream>>>(ob, nbr, wfrag + 2 * FR, rb, part);
    reduce_k<<<32, 256, 0, stream>>>(part, S);
    apply_k<<<3125, 256, 0, stream>>>(rb, S, gs + 16, bs + 16, xb, xb, nullptr);

    // L3: o = relu(bn(conv(x1)))                  -> ob
    conv_k<<<CBLK, 256, 0, stream>>>(xb, nbr, wfrag + 3 * FR, rb, part);
    reduce_k<<<32, 256, 0, stream>>>(part, S);
    apply_k<<<3125, 256, 0, stream>>>(rb, S, gs + 32, bs + 32, nullptr, ob, nullptr);

    // L4: out = relu(bn(conv(o)) + x1)            -> d_out (f32)
    conv_k<<<CBLK, 256, 0, stream>>>(ob, nbr, wfrag + 4 * FR, rb, part);
    reduce_k<<<32, 256, 0, stream>>>(part, S);
    apply_k<<<3125, 256, 0, stream>>>(rb, S, gs + 48, bs + 48, xb, nullptr, out);
}